// Round 2
// baseline (1359.391 us; speedup 1.0000x reference)
//
#include <hip/hip_runtime.h>
#include <stdint.h>
#include <stddef.h>

// ---------------------------------------------------------------------------
// EnhancedSpatialAttention fused kernel for MI355X (gfx950).
//   prep_kernel : f32->bf16 weight conversion + head-mean rel-pos bias.
//   attn_main   : one block per sequence (N=2048), 256 thr (4 waves),
//                 per-head {QKV proj -> scores+softmax -> PV -> out-proj acc},
//                 epilogue residual + LayerNorm from registers.
// ---------------------------------------------------------------------------

typedef __attribute__((ext_vector_type(8))) short short8;    // 8 bf16 (4 VGPR)
typedef __attribute__((ext_vector_type(4))) float f32x4;     // MFMA C/D frag
typedef __attribute__((ext_vector_type(4))) unsigned short ushort4v;

__device__ __forceinline__ unsigned short f2bf(float f) {
  unsigned u = __builtin_bit_cast(unsigned, f);
  u = (u + 0x7FFFu + ((u >> 16) & 1u)) >> 16;   // RNE
  return (unsigned short)u;
}

__device__ __forceinline__ f32x4 mfma16(short8 a, short8 b, f32x4 c) {
  return __builtin_amdgcn_mfma_f32_16x16x32_bf16(a, b, c, 0, 0, 0);
}

// ---- LDS staging: [64 rows][256 cols bf16] chunk of a row-stride-512 matrix.
// 16B-unit XOR swizzle (low 3 bits ^ row&7) -> conflict-free ds_read_b128.
__device__ __forceinline__ void stage_w_64x256(const unsigned short* __restrict__ W,
                                               int rowbase, int colbase,
                                               char* ws, int tid) {
#pragma unroll
  for (int it = 0; it < 8; ++it) {
    int flat = it * 256 + tid;        // 2048 16B units
    int r = flat >> 5;                // 0..63
    int u = flat & 31;                // unit in row
    int us = (u & 24) | ((u ^ r) & 7);
    uint4 val = *(const uint4*)(W + (size_t)(rowbase + r) * 512 + colbase + u * 8);
    *(uint4*)(ws + r * 512 + us * 16) = val;
  }
}

// ---- LDS staging: [256 rows][64 cols bf16] chunk (for out_proj weights).
__device__ __forceinline__ void stage_wo_256x64(const unsigned short* __restrict__ W,
                                                int rowbase, int colbase,
                                                char* ws, int tid) {
#pragma unroll
  for (int it = 0; it < 8; ++it) {
    int flat = it * 256 + tid;        // 2048 16B units
    int r = flat >> 3;                // 0..255
    int u = flat & 7;
    int us = u ^ (r & 7);
    uint4 val = *(const uint4*)(W + (size_t)(rowbase + r) * 512 + colbase + u * 8);
    *(uint4*)(ws + r * 128 + us * 16) = val;
  }
}

__device__ __forceinline__ short8 rd_w_64x256(const char* ws, int rB, int kg) {
  int us = (kg & 24) | ((kg ^ rB) & 7);
  return *(const short8*)(ws + rB * 512 + us * 16);
}
__device__ __forceinline__ short8 rd_wo(const char* ws, int rB, int kg) {
  int us = kg ^ (rB & 7);
  return *(const short8*)(ws + rB * 128 + us * 16);
}
// 64x64 bf16 scratch with 72-element (144B) row stride: uniform-minimal banks.
__device__ __forceinline__ short8 rd72(const char* buf, int row, int kelem) {
  return *(const short8*)(buf + row * 144 + kelem * 2);
}

// Shared 64-col x 512-k projection: out[nt] += x @ W[rowbase..+64]^T
__device__ __forceinline__ void proj64(const unsigned short* __restrict__ W, int rowbase,
                                       const short8* xf, char* WS, int tid, int l15, int g,
                                       f32x4 acc[4]) {
#pragma unroll
  for (int c = 0; c < 2; ++c) {
    stage_w_64x256(W, rowbase, c * 256, WS, tid);
    __syncthreads();
#pragma unroll
    for (int ks = 0; ks < 8; ++ks) {
      short8 af = xf[c * 8 + ks];
#pragma unroll
      for (int nt = 0; nt < 4; ++nt) {
        short8 bf = rd_w_64x256(WS, nt * 16 + l15, ks * 4 + g);
        acc[nt] = mfma16(af, bf, acc[nt]);
      }
    }
    __syncthreads();
  }
}

__global__ void prep_kernel(const float* __restrict__ wqkv_f,
                            const float* __restrict__ wo_f,
                            const float* __restrict__ rel,
                            unsigned short* __restrict__ wbf,
                            unsigned short* __restrict__ wobf,
                            float* __restrict__ bias2d) {
  int b = blockIdx.x, tid = threadIdx.x;
  if (b < 512) {
    int base = (b * 256 + tid) * 8;   // 8 elems/thread; 512*256*8 = 1048576
    const float* src;
    unsigned short* dst;
    int off;
    if (base < 1536 * 512) { src = wqkv_f; dst = wbf; off = base; }
    else { src = wo_f; dst = wobf; off = base - 1536 * 512; }
    float4 a = *(const float4*)(src + off);
    float4 c = *(const float4*)(src + off + 4);
    unsigned p0 = (unsigned)f2bf(a.x) | ((unsigned)f2bf(a.y) << 16);
    unsigned p1 = (unsigned)f2bf(a.z) | ((unsigned)f2bf(a.w) << 16);
    unsigned p2 = (unsigned)f2bf(c.x) | ((unsigned)f2bf(c.y) << 16);
    unsigned p3 = (unsigned)f2bf(c.z) | ((unsigned)f2bf(c.w) << 16);
    *(uint4*)(dst + off) = make_uint4(p0, p1, p2, p3);
  } else {
    int idx = (b - 512) * 256 + tid;  // 0..4095
    int m = idx >> 6, nn = idx & 63;
    float s = 0.f;
#pragma unroll
    for (int hh = 0; hh < 8; ++hh) s += rel[hh * 16384 + m * 128 + nn];
    bias2d[idx] = s * 0.125f;
  }
}

__global__ __launch_bounds__(256, 2) void attn_main(
    const float* __restrict__ x,            // [2048,64,512] f32
    const unsigned short* __restrict__ wqkv,// bf16 [1536,512]
    const float* __restrict__ bqkv,         // [1536]
    const unsigned short* __restrict__ wo,  // bf16 [512,512]
    const float* __restrict__ bo,           // [512]
    const float* __restrict__ lng,
    const float* __restrict__ lnb,
    const float* __restrict__ bias2d,       // [64,64] f32
    float* __restrict__ out) {
  // LDS: B0/B1/B2 = 64x72 bf16 scratch (9216B each), WS = 32KB weight stage.
  __shared__ __attribute__((aligned(16))) char smem[60416];
  char* B0 = smem;            // Qs, then P
  char* B1 = smem + 9216;     // Ks, then ctx_h
  char* B2 = smem + 18432;    // V^T
  char* WS = smem + 27648;

  const int n = blockIdx.x;
  const int tid = threadIdx.x;
  const int w = tid >> 6;       // wave id (0..3), owns output rows w*16..w*16+15
  const int lane = tid & 63;
  const int l15 = lane & 15;
  const int g = lane >> 4;
  const int mrow = w * 16 + g * 4;   // C-layout row base for this lane

  // ---- x A-fragments (rows w*16+l15, bf16) held in registers: 16 x short8.
  const float* xrow = x + ((size_t)n * 64 + (size_t)(w * 16 + l15)) * 512;
  short8 xf[16];
#pragma unroll
  for (int ks = 0; ks < 16; ++ks) {
    float4 a = *(const float4*)(xrow + ks * 32 + g * 8);
    float4 b = *(const float4*)(xrow + ks * 32 + g * 8 + 4);
    short8 s;
    s[0] = (short)f2bf(a.x); s[1] = (short)f2bf(a.y);
    s[2] = (short)f2bf(a.z); s[3] = (short)f2bf(a.w);
    s[4] = (short)f2bf(b.x); s[5] = (short)f2bf(b.y);
    s[6] = (short)f2bf(b.z); s[7] = (short)f2bf(b.w);
    xf[ks] = s;
  }

  f32x4 oacc[32] = {};   // attn_out accumulator: rows mrow..mrow+3 x 512 cols

  for (int h = 0; h < 8; ++h) {
    // ================= Q =================
    {
      f32x4 qa[4] = {};
      proj64(wqkv, h * 64, xf, WS, tid, l15, g, qa);
#pragma unroll
      for (int nt = 0; nt < 4; ++nt) {
        float bq = bqkv[h * 64 + nt * 16 + l15];
#pragma unroll
        for (int r = 0; r < 4; ++r)
          *(unsigned short*)(B0 + (mrow + r) * 144 + (nt * 16 + l15) * 2) =
              f2bf(qa[nt][r] + bq);
      }
    }
    // ================= K =================
    {
      f32x4 ka[4] = {};
      proj64(wqkv, 512 + h * 64, xf, WS, tid, l15, g, ka);
#pragma unroll
      for (int nt = 0; nt < 4; ++nt) {
        float bk = bqkv[512 + h * 64 + nt * 16 + l15];
#pragma unroll
        for (int r = 0; r < 4; ++r)
          *(unsigned short*)(B1 + (mrow + r) * 144 + (nt * 16 + l15) * 2) =
              f2bf(ka[nt][r] + bk);
      }
    }
    // ================= V (stored transposed) =================
    {
      f32x4 va[4] = {};
      proj64(wqkv, 1024 + h * 64, xf, WS, tid, l15, g, va);
#pragma unroll
      for (int nt = 0; nt < 4; ++nt) {
        float bv = bqkv[1024 + h * 64 + nt * 16 + l15];
        ushort4v pk;
        pk.x = f2bf(va[nt][0] + bv); pk.y = f2bf(va[nt][1] + bv);
        pk.z = f2bf(va[nt][2] + bv); pk.w = f2bf(va[nt][3] + bv);
        // Vt[d][m..m+3], d = nt*16+l15, m = mrow
        *(ushort4v*)(B2 + (nt * 16 + l15) * 144 + mrow * 2) = pk;
      }
    }
    __syncthreads();   // K and V^T visible to all waves

    // ================= scores + softmax =================
    {
      f32x4 sc[4] = {};
      short8 aq0 = rd72(B0, w * 16 + l15, g * 8);
      short8 aq1 = rd72(B0, w * 16 + l15, 32 + g * 8);
#pragma unroll
      for (int nt = 0; nt < 4; ++nt)
        sc[nt] = mfma16(aq0, rd72(B1, nt * 16 + l15, g * 8), sc[nt]);
#pragma unroll
      for (int nt = 0; nt < 4; ++nt)
        sc[nt] = mfma16(aq1, rd72(B1, nt * 16 + l15, 32 + g * 8), sc[nt]);

      float mx[4] = {-1e30f, -1e30f, -1e30f, -1e30f};
#pragma unroll
      for (int nt = 0; nt < 4; ++nt) {
#pragma unroll
        for (int r = 0; r < 4; ++r) {
          float bz = bias2d[(mrow + r) * 64 + nt * 16 + l15];
          float v = sc[nt][r] * 0.125f + bz;
          sc[nt][r] = v;
          mx[r] = fmaxf(mx[r], v);
        }
      }
#pragma unroll
      for (int mk = 1; mk < 16; mk <<= 1) {
#pragma unroll
        for (int r = 0; r < 4; ++r) mx[r] = fmaxf(mx[r], __shfl_xor(mx[r], mk));
      }
      float sm[4] = {0.f, 0.f, 0.f, 0.f};
#pragma unroll
      for (int nt = 0; nt < 4; ++nt) {
#pragma unroll
        for (int r = 0; r < 4; ++r) {
          float e = __expf(sc[nt][r] - mx[r]);
          sc[nt][r] = e;
          sm[r] += e;
        }
      }
#pragma unroll
      for (int mk = 1; mk < 16; mk <<= 1) {
#pragma unroll
        for (int r = 0; r < 4; ++r) sm[r] += __shfl_xor(sm[r], mk);
      }
      float inv[4];
#pragma unroll
      for (int r = 0; r < 4; ++r) inv[r] = 1.0f / sm[r];
#pragma unroll
      for (int nt = 0; nt < 4; ++nt) {
#pragma unroll
        for (int r = 0; r < 4; ++r)
          *(unsigned short*)(B0 + (mrow + r) * 144 + (nt * 16 + l15) * 2) =
              f2bf(sc[nt][r] * inv[r]);
      }
    }
    __syncthreads();   // all waves done reading Ks(B1) before ctx_h overwrites it

    // ================= PV =================
    {
      f32x4 cv[4] = {};
      short8 ap0 = rd72(B0, w * 16 + l15, g * 8);
      short8 ap1 = rd72(B0, w * 16 + l15, 32 + g * 8);
#pragma unroll
      for (int nt = 0; nt < 4; ++nt)
        cv[nt] = mfma16(ap0, rd72(B2, nt * 16 + l15, g * 8), cv[nt]);
#pragma unroll
      for (int nt = 0; nt < 4; ++nt)
        cv[nt] = mfma16(ap1, rd72(B2, nt * 16 + l15, 32 + g * 8), cv[nt]);
#pragma unroll
      for (int nt = 0; nt < 4; ++nt) {
#pragma unroll
        for (int r = 0; r < 4; ++r)
          *(unsigned short*)(B1 + (mrow + r) * 144 + (nt * 16 + l15) * 2) =
              f2bf(cv[nt][r]);
      }
    }

    // ================= out-proj accumulate =================
#pragma unroll
    for (int c = 0; c < 2; ++c) {
      stage_wo_256x64(wo, c * 256, h * 64, WS, tid);
      __syncthreads();
      short8 ac0 = rd72(B1, w * 16 + l15, g * 8);
      short8 ac1 = rd72(B1, w * 16 + l15, 32 + g * 8);
#pragma unroll
      for (int nt2 = 0; nt2 < 16; ++nt2) {
        oacc[c * 16 + nt2] = mfma16(ac0, rd_wo(WS, nt2 * 16 + l15, g), oacc[c * 16 + nt2]);
        oacc[c * 16 + nt2] = mfma16(ac1, rd_wo(WS, nt2 * 16 + l15, 4 + g), oacc[c * 16 + nt2]);
      }
      __syncthreads();
    }
  }

  // ================= epilogue: +bias, +residual, LayerNorm =================
  float s1[4] = {0.f, 0.f, 0.f, 0.f}, s2[4] = {0.f, 0.f, 0.f, 0.f};
  const float* xblk = x + (size_t)n * 64 * 512;
#pragma unroll
  for (int i = 0; i < 32; ++i) {
    int d = i * 16 + l15;
    float bov = bo[d];
#pragma unroll
    for (int r = 0; r < 4; ++r) {
      float xv = xblk[(size_t)(mrow + r) * 512 + d];
      float v = oacc[i][r] + bov + xv;
      oacc[i][r] = v;
      s1[r] += v;
      s2[r] += v * v;
    }
  }
#pragma unroll
  for (int mk = 1; mk < 16; mk <<= 1) {
#pragma unroll
    for (int r = 0; r < 4; ++r) {
      s1[r] += __shfl_xor(s1[r], mk);
      s2[r] += __shfl_xor(s2[r], mk);
    }
  }
  float mu[4], rs[4];
#pragma unroll
  for (int r = 0; r < 4; ++r) {
    mu[r] = s1[r] * (1.0f / 512.0f);
    float var = s2[r] * (1.0f / 512.0f) - mu[r] * mu[r];
    rs[r] = rsqrtf(var + 1e-5f);
  }
  float* oblk = out + (size_t)n * 64 * 512;
#pragma unroll
  for (int i = 0; i < 32; ++i) {
    int d = i * 16 + l15;
    float gg = lng[d], bb = lnb[d];
#pragma unroll
    for (int r = 0; r < 4; ++r)
      oblk[(size_t)(mrow + r) * 512 + d] = (oacc[i][r] - mu[r]) * rs[r] * gg + bb;
  }
}

extern "C" void kernel_launch(void* const* d_in, const int* in_sizes, int n_in,
                              void* d_out, int out_size, void* d_ws, size_t ws_size,
                              hipStream_t stream) {
  const float* x    = (const float*)d_in[0];
  const float* wqkv = (const float*)d_in[1];
  const float* bqkv = (const float*)d_in[2];
  const float* wo   = (const float*)d_in[3];
  const float* bo   = (const float*)d_in[4];
  const float* lng  = (const float*)d_in[5];
  const float* lnb  = (const float*)d_in[6];
  const float* rel  = (const float*)d_in[7];

  // workspace layout (bytes): wqkv bf16 [0,1572864) | wo bf16 [.. +524288) | bias f32 16KB
  unsigned short* wbf  = (unsigned short*)d_ws;
  unsigned short* wobf = wbf + 1536 * 512;
  float* bias2d = (float*)(wobf + 512 * 512);

  prep_kernel<<<528, 256, 0, stream>>>(wqkv, wo, rel, wbf, wobf, bias2d);
  attn_main<<<2048, 256, 0, stream>>>(x, wbf, bqkv, wobf, bo, lng, lnb, bias2d,
                                      (float*)d_out);
}

// Round 3
// 621.327 us; speedup vs baseline: 2.1879x; 2.1879x over previous
//
#include <hip/hip_runtime.h>
#include <stdint.h>
#include <stddef.h>

// ---------------------------------------------------------------------------
// EnhancedSpatialAttention fused kernel for MI355X (gfx950), round 3.
//   prep_kernel : weights -> bf16, pre-tiled into 16KB staging chunks with the
//                 LDS read-swizzle pre-applied to the GLOBAL layout, so
//                 attn_main can use linear global_load_lds staging.
//   attn_main   : one block per sequence, 4 waves; 128 uniform chunk-bodies
//                 (16 MFMA each) driven by a double-buffered global_load_lds
//                 pipeline with counted vmcnt (never drained in-loop);
//                 attention phases run in the load-shadow; coalesced epilogue.
// ---------------------------------------------------------------------------

typedef __attribute__((ext_vector_type(8))) short short8;    // 8 bf16
typedef __attribute__((ext_vector_type(4))) float f32x4;     // MFMA C/D frag

typedef __attribute__((address_space(3))) unsigned int as3_u32;
typedef __attribute__((address_space(1))) unsigned int as1_u32;

#define VMCNT4 asm volatile("s_waitcnt vmcnt(4)" ::: "memory")
#define VMCNT0 asm volatile("s_waitcnt vmcnt(0)" ::: "memory")
#define LGKM0  asm volatile("s_waitcnt lgkmcnt(0)" ::: "memory")
#define BARR() __builtin_amdgcn_s_barrier()
#define PRIO1  __builtin_amdgcn_s_setprio(1)
#define PRIO0  __builtin_amdgcn_s_setprio(0)

__device__ __forceinline__ unsigned short f2bf(float f) {
  unsigned u = __builtin_bit_cast(unsigned, f);
  u = (u + 0x7FFFu + ((u >> 16) & 1u)) >> 16;   // RNE
  return (unsigned short)u;
}

__device__ __forceinline__ f32x4 mfma16(short8 a, short8 b, f32x4 c) {
  return __builtin_amdgcn_mfma_f32_16x16x32_bf16(a, b, c, 0, 0, 0);
}

// 64-row x 72-elem (144B, 16B-aligned stride) bf16 scratch read.
__device__ __forceinline__ short8 rd72(const char* buf, int row, int kelem) {
  return *(const short8*)(buf + row * 144 + kelem * 2);
}

// Stage one 16KB chunk: 4 x global_load_lds dwordx4 per thread, linear LDS.
__device__ __forceinline__ void stage4(char* ldsbase, const char* gsrc, int w, int lane) {
#pragma unroll
  for (int j = 0; j < 4; ++j) {
    int off = j * 4096 + w * 1024;
    __builtin_amdgcn_global_load_lds((const as1_u32*)(gsrc + off + lane * 16),
                                     (as3_u32*)(ldsbase + off), 16, 0, 0);
  }
}

// QKV chunk [64 wrows x 128 kcols]: 16 MFMAs, B-frag swizzle us=(kg&8)|((kg^row)&7)
__device__ __forceinline__ void qkv_chunk(const char* ws, const short8* xfp,
                                          int l15, int g, f32x4* acc) {
#pragma unroll
  for (int ks = 0; ks < 4; ++ks) {
    short8 a = xfp[ks];
#pragma unroll
    for (int nt = 0; nt < 4; ++nt) {
      int row = nt * 16 + l15;
      int kg = ks * 4 + g;
      int us = (kg & 8) | ((kg ^ row) & 7);
      short8 b = *(const short8*)(ws + row * 256 + us * 16);
      acc[nt] = mfma16(a, b, acc[nt]);
    }
  }
}

// Out-proj chunk [128 N-rows x 64 kcols]: 16 MFMAs, swizzle us=(kg^row)&7
__device__ __forceinline__ void oproj_chunk(const char* ws, short8 af0, short8 af1,
                                            int l15, int g, f32x4* oaccp) {
#pragma unroll
  for (int nt2 = 0; nt2 < 8; ++nt2) {
    int row = nt2 * 16 + l15;
    int us0 = (g ^ row) & 7;
    int us1 = ((4 + g) ^ row) & 7;
    short8 b0 = *(const short8*)(ws + row * 128 + us0 * 16);
    oaccp[nt2] = mfma16(af0, b0, oaccp[nt2]);
    short8 b1 = *(const short8*)(ws + row * 128 + us1 * 16);
    oaccp[nt2] = mfma16(af1, b1, oaccp[nt2]);
  }
}

__global__ void prep_kernel(const float* __restrict__ wqkv_f,
                            const float* __restrict__ wo_f,
                            const float* __restrict__ rel,
                            unsigned short* __restrict__ wt,
                            float* __restrict__ bias2d) {
  int b = blockIdx.x, tid = threadIdx.x;
  if (b < 128) {
    // chunk b: head h = b>>4, idx i = b&15. i<12: QKV (rg=i>>2, kc=i&3); else oproj nc=i-12
    int h = b >> 4, i = b & 15;
    unsigned short* dst = wt + (size_t)b * 8192;
#pragma unroll
    for (int t = 0; t < 4; ++t) {
      int u = t * 256 + tid;          // unit 0..1023 (16B each)
      const float* src;
      if (i < 12) {
        int rg = i >> 2, kc = i & 3;
        int row = u >> 4, us = u & 15;
        int kg = (us & 8) | ((us ^ row) & 7);
        src = wqkv_f + (size_t)(rg * 512 + h * 64 + row) * 512 + kc * 128 + kg * 8;
      } else {
        int nc = i - 12;
        int row = u >> 3, us = u & 7;
        int kg = (us ^ row) & 7;
        src = wo_f + (size_t)(nc * 128 + row) * 512 + h * 64 + kg * 8;
      }
      float4 a = *(const float4*)src;
      float4 c = *(const float4*)(src + 4);
      unsigned p0 = (unsigned)f2bf(a.x) | ((unsigned)f2bf(a.y) << 16);
      unsigned p1 = (unsigned)f2bf(a.z) | ((unsigned)f2bf(a.w) << 16);
      unsigned p2 = (unsigned)f2bf(c.x) | ((unsigned)f2bf(c.y) << 16);
      unsigned p3 = (unsigned)f2bf(c.z) | ((unsigned)f2bf(c.w) << 16);
      *(uint4*)(dst + u * 8) = make_uint4(p0, p1, p2, p3);
    }
  } else {
    int idx = (b - 128) * 256 + tid;  // 0..4095
    int m = idx >> 6, nn = idx & 63;
    float s = 0.f;
#pragma unroll
    for (int hh = 0; hh < 8; ++hh) s += rel[hh * 16384 + m * 128 + nn];
    bias2d[idx] = s * 0.125f;
  }
}

__global__ __launch_bounds__(256, 2) void attn_main(
    const float* __restrict__ x,        // [2048,64,512] f32
    const char* __restrict__ wq,        // 128 pre-tiled 16KB chunks (bf16)
    const float* __restrict__ bqkv,     // [1536]
    const float* __restrict__ bo,       // [512]
    const float* __restrict__ lng,
    const float* __restrict__ lnb,
    const float* __restrict__ bias2d,   // [64,64]
    float* __restrict__ out) {
  // LDS: B0 [0,9216) B1 [9216,18432) WS 2x16KB [18432,51200). EP overlays WS.
  __shared__ __attribute__((aligned(16))) char smem[51200];
  char* B0 = smem;
  char* B1 = smem + 9216;
  char* WSb = smem + 18432;

  const int n = blockIdx.x;
  const int tid = threadIdx.x;
  const int w = tid >> 6, lane = tid & 63;
  const int l15 = lane & 15, g = lane >> 4;
  const int mrow = w * 16 + g * 4;     // C-frag row base
  const int wrow = w * 16 + l15;       // A-frag row

  // ---- bias2d into 16 regs (avoids vmem ops inside the pipelined loop)
  float b2d[16];
#pragma unroll
  for (int nt = 0; nt < 4; ++nt)
#pragma unroll
    for (int r = 0; r < 4; ++r)
      b2d[nt * 4 + r] = bias2d[(mrow + r) * 64 + nt * 16 + l15];

  // ---- x A-fragments: row wrow, xf[i] = cols i*32 + g*8 .. +8
  const float* xrow = x + ((size_t)n * 64 + wrow) * 512;
  short8 xf[16];
#pragma unroll
  for (int ks = 0; ks < 16; ++ks) {
    float4 a = *(const float4*)(xrow + ks * 32 + g * 8);
    float4 b = *(const float4*)(xrow + ks * 32 + g * 8 + 4);
    short8 s;
    s[0] = (short)f2bf(a.x); s[1] = (short)f2bf(a.y);
    s[2] = (short)f2bf(a.z); s[3] = (short)f2bf(a.w);
    s[4] = (short)f2bf(b.x); s[5] = (short)f2bf(b.y);
    s[6] = (short)f2bf(b.z); s[7] = (short)f2bf(b.w);
    xf[ks] = s;
  }

  f32x4 oacc[32] = {};    // attn_out: rows mrow..+3, col block j -> j*16+l15

  stage4(WSb, wq, w, lane);          // prologue: chunk 0 -> buf 0

  for (int h = 0; h < 8; ++h) {
    const char* wh = wq + (size_t)h * 262144;
    // ================= Q : bodies 0..3 =================
    {
      f32x4 qa[4] = {}; float bq[4];
#pragma unroll
      for (int i = 0; i < 4; ++i) {
        if (i == 3) {
#pragma unroll
          for (int nt = 0; nt < 4; ++nt) bq[nt] = bqkv[h * 64 + nt * 16 + l15];
        }
        stage4(WSb + (((i + 1) & 1) << 14), wh + (size_t)(i + 1) * 16384, w, lane);
        VMCNT4; BARR();
        PRIO1; qkv_chunk(WSb + ((i & 1) << 14), &xf[i * 4], l15, g, qa); PRIO0;
        if (i == 3) {
#pragma unroll
          for (int nt = 0; nt < 4; ++nt)
#pragma unroll
            for (int r = 0; r < 4; ++r)
              *(unsigned short*)(B0 + (mrow + r) * 144 + (nt * 16 + l15) * 2) =
                  f2bf(qa[nt][r] + bq[nt]);
        }
        LGKM0; BARR();
      }
    }
    // ================= K : bodies 4..7 =================
    {
      f32x4 ka[4] = {}; float bk[4];
#pragma unroll
      for (int i = 0; i < 4; ++i) {
        if (i == 3) {
#pragma unroll
          for (int nt = 0; nt < 4; ++nt) bk[nt] = bqkv[512 + h * 64 + nt * 16 + l15];
        }
        stage4(WSb + (((i + 1) & 1) << 14), wh + (size_t)(5 + i) * 16384, w, lane);
        VMCNT4; BARR();
        PRIO1; qkv_chunk(WSb + ((i & 1) << 14), &xf[i * 4], l15, g, ka); PRIO0;
        if (i == 3) {
#pragma unroll
          for (int nt = 0; nt < 4; ++nt)
#pragma unroll
            for (int r = 0; r < 4; ++r)
              *(unsigned short*)(B1 + (mrow + r) * 144 + (nt * 16 + l15) * 2) =
                  f2bf(ka[nt][r] + bk[nt]);
        }
        LGKM0; BARR();
      }
    }
    // ================= V : bodies 8..11 (scores in body 8's load-shadow) ====
    {
      f32x4 va[4] = {}; float bv[4];
#pragma unroll
      for (int i = 0; i < 4; ++i) {
        if (i == 3) {
#pragma unroll
          for (int nt = 0; nt < 4; ++nt) bv[nt] = bqkv[1024 + h * 64 + nt * 16 + l15];
        }
        stage4(WSb + (((i + 1) & 1) << 14), wh + (size_t)(9 + i) * 16384, w, lane);
        if (i == 0) {
          // ---- scores + softmax (reads B0=Q own rows, B1=K all rows; P->B0)
          f32x4 sc[4] = {};
          short8 aq0 = rd72(B0, wrow, g * 8);
          short8 aq1 = rd72(B0, wrow, 32 + g * 8);
#pragma unroll
          for (int nt = 0; nt < 4; ++nt)
            sc[nt] = mfma16(aq0, rd72(B1, nt * 16 + l15, g * 8), sc[nt]);
#pragma unroll
          for (int nt = 0; nt < 4; ++nt)
            sc[nt] = mfma16(aq1, rd72(B1, nt * 16 + l15, 32 + g * 8), sc[nt]);
          float mx[4] = {-1e30f, -1e30f, -1e30f, -1e30f};
#pragma unroll
          for (int nt = 0; nt < 4; ++nt)
#pragma unroll
            for (int r = 0; r < 4; ++r) {
              float v = sc[nt][r] * 0.125f + b2d[nt * 4 + r];
              sc[nt][r] = v;
              mx[r] = fmaxf(mx[r], v);
            }
#pragma unroll
          for (int mk = 1; mk < 16; mk <<= 1)
#pragma unroll
            for (int r = 0; r < 4; ++r) mx[r] = fmaxf(mx[r], __shfl_xor(mx[r], mk));
          float sm[4] = {0.f, 0.f, 0.f, 0.f};
#pragma unroll
          for (int nt = 0; nt < 4; ++nt)
#pragma unroll
            for (int r = 0; r < 4; ++r) {
              float e = __expf(sc[nt][r] - mx[r]);
              sc[nt][r] = e;
              sm[r] += e;
            }
#pragma unroll
          for (int mk = 1; mk < 16; mk <<= 1)
#pragma unroll
            for (int r = 0; r < 4; ++r) sm[r] += __shfl_xor(sm[r], mk);
          float inv[4];
#pragma unroll
          for (int r = 0; r < 4; ++r) inv[r] = 1.0f / sm[r];
#pragma unroll
          for (int nt = 0; nt < 4; ++nt)
#pragma unroll
            for (int r = 0; r < 4; ++r)
              *(unsigned short*)(B0 + (mrow + r) * 144 + (nt * 16 + l15) * 2) =
                  f2bf(sc[nt][r] * inv[r]);
        }
        VMCNT4; BARR();
        PRIO1; qkv_chunk(WSb + ((i & 1) << 14), &xf[i * 4], l15, g, va); PRIO0;
        if (i == 3) {  // V^T into B1 (K dead): B1[d][m]
#pragma unroll
          for (int nt = 0; nt < 4; ++nt) {
            unsigned short p0 = f2bf(va[nt][0] + bv[nt]);
            unsigned short p1 = f2bf(va[nt][1] + bv[nt]);
            unsigned short p2 = f2bf(va[nt][2] + bv[nt]);
            unsigned short p3 = f2bf(va[nt][3] + bv[nt]);
            unsigned lo = (unsigned)p0 | ((unsigned)p1 << 16);
            unsigned hi = (unsigned)p2 | ((unsigned)p3 << 16);
            *(uint2*)(B1 + (nt * 16 + l15) * 144 + mrow * 2) = make_uint2(lo, hi);
          }
        }
        LGKM0; BARR();
      }
    }
    // ================= O : bodies 12..15 (PV in body 12's load-shadow) =====
    {
      short8 af0, af1;
#pragma unroll
      for (int i = 0; i < 4; ++i) {
        bool dostage = (i < 3) || (h < 7);
        if (dostage)
          stage4(WSb + (((i + 1) & 1) << 14), wh + (size_t)(13 + i) * 16384, w, lane);
        if (i == 0) {
          // ---- PV: ctx = P @ V  (B0=P own rows, B1=V^T all rows) -> ctx->B0
          f32x4 cv[4] = {};
          short8 ap0 = rd72(B0, wrow, g * 8);
          short8 ap1 = rd72(B0, wrow, 32 + g * 8);
#pragma unroll
          for (int nt = 0; nt < 4; ++nt)
            cv[nt] = mfma16(ap0, rd72(B1, nt * 16 + l15, g * 8), cv[nt]);
#pragma unroll
          for (int nt = 0; nt < 4; ++nt)
            cv[nt] = mfma16(ap1, rd72(B1, nt * 16 + l15, 32 + g * 8), cv[nt]);
#pragma unroll
          for (int nt = 0; nt < 4; ++nt)
#pragma unroll
            for (int r = 0; r < 4; ++r)
              *(unsigned short*)(B0 + (mrow + r) * 144 + (nt * 16 + l15) * 2) =
                  f2bf(cv[nt][r]);
        }
        if (dostage) { VMCNT4; } else { VMCNT0; }
        BARR();
        if (i == 0) {  // ctx A-frags (own rows), reused for all 4 bodies
          af0 = rd72(B0, wrow, g * 8);
          af1 = rd72(B0, wrow, 32 + g * 8);
        }
        PRIO1; oproj_chunk(WSb + ((i & 1) << 14), af0, af1, l15, g, &oacc[i * 8]); PRIO0;
        LGKM0; BARR();
      }
    }
  }

  // ================= epilogue: +bo, +residual, LayerNorm (coalesced) ========
  float* EP = (float*)(smem + 18432);   // [64][68] f32 tile (17408 B, in WS area)
  float s1[4] = {0.f, 0.f, 0.f, 0.f}, s2[4] = {0.f, 0.f, 0.f, 0.f};
  const float* xblk = x + (size_t)n * 32768;
  float* oblk = out + (size_t)n * 32768;
#pragma unroll
  for (int cc = 0; cc < 8; ++cc) {
#pragma unroll
    for (int t = 0; t < 4; ++t) {
      int flat = t * 256 + tid;
      int row = flat >> 4, f4 = flat & 15;
      float4 v = *(const float4*)(xblk + row * 512 + cc * 64 + f4 * 4);
      *(float4*)(EP + row * 68 + f4 * 4) = v;
    }
    __syncthreads();
#pragma unroll
    for (int i2 = 0; i2 < 4; ++i2) {
      int d = cc * 64 + i2 * 16 + l15;
      float bov = bo[d];
#pragma unroll
      for (int r = 0; r < 4; ++r) {
        float xv = EP[(mrow + r) * 68 + i2 * 16 + l15];
        float v = oacc[cc * 4 + i2][r] + bov + xv;
        oacc[cc * 4 + i2][r] = v;
        s1[r] += v;
        s2[r] += v * v;
      }
    }
    __syncthreads();
  }
#pragma unroll
  for (int mk = 1; mk < 16; mk <<= 1)
#pragma unroll
    for (int r = 0; r < 4; ++r) {
      s1[r] += __shfl_xor(s1[r], mk);
      s2[r] += __shfl_xor(s2[r], mk);
    }
  float mu[4], rs[4];
#pragma unroll
  for (int r = 0; r < 4; ++r) {
    mu[r] = s1[r] * (1.0f / 512.0f);
    float var = s2[r] * (1.0f / 512.0f) - mu[r] * mu[r];
    rs[r] = rsqrtf(var + 1e-5f);
  }
#pragma unroll
  for (int cc = 0; cc < 8; ++cc) {
#pragma unroll
    for (int i2 = 0; i2 < 4; ++i2) {
      int d = cc * 64 + i2 * 16 + l15;
      float gg = lng[d], bb = lnb[d];
#pragma unroll
      for (int r = 0; r < 4; ++r)
        EP[(mrow + r) * 68 + i2 * 16 + l15] =
            (oacc[cc * 4 + i2][r] - mu[r]) * rs[r] * gg + bb;
    }
    __syncthreads();
#pragma unroll
    for (int t = 0; t < 4; ++t) {
      int flat = t * 256 + tid;
      int row = flat >> 4, f4 = flat & 15;
      *(float4*)(oblk + row * 512 + cc * 64 + f4 * 4) =
          *(const float4*)(EP + row * 68 + f4 * 4);
    }
    __syncthreads();
  }
}

extern "C" void kernel_launch(void* const* d_in, const int* in_sizes, int n_in,
                              void* d_out, int out_size, void* d_ws, size_t ws_size,
                              hipStream_t stream) {
  const float* x    = (const float*)d_in[0];
  const float* wqkv = (const float*)d_in[1];
  const float* bqkv = (const float*)d_in[2];
  const float* wo   = (const float*)d_in[3];
  const float* bo   = (const float*)d_in[4];
  const float* lng  = (const float*)d_in[5];
  const float* lnb  = (const float*)d_in[6];
  const float* rel  = (const float*)d_in[7];

  // ws: 128 x 16KB weight chunks [0, 2097152) | bias2d f32 [.. +16384)
  unsigned short* wt = (unsigned short*)d_ws;
  float* bias2d = (float*)((char*)d_ws + 2097152);

  prep_kernel<<<144, 256, 0, stream>>>(wqkv, wo, rel, wt, bias2d);
  attn_main<<<2048, 256, 0, stream>>>(x, (const char*)d_ws, bqkv, bo, lng, lnb,
                                      bias2d, (float*)d_out);
}

// Round 4
// 578.191 us; speedup vs baseline: 2.3511x; 1.0746x over previous
//
#include <hip/hip_runtime.h>
#include <stdint.h>
#include <stddef.h>

// ---------------------------------------------------------------------------
// EnhancedSpatialAttention, round 4: 3-kernel split for MI355X (gfx950).
//   prep_kernel : weights -> bf16 pre-tiled/pre-swizzled 16KB chunks + bias2d.
//   attn_qkv    : per-sequence fused QKV proj (2Mx2N waves, halved LDS B-reads,
//                 double-buffered global_load_lds, counted vmcnt) + attention;
//                 writes ctx bf16 into d_out's per-sequence front half.
//   oproj_ln    : per-sequence pipelined GEMM ctx@Wo^T + bias + residual + LN,
//                 in-place over d_out.
// ---------------------------------------------------------------------------

typedef __attribute__((ext_vector_type(8))) short short8;    // 8 bf16
typedef __attribute__((ext_vector_type(4))) float f32x4;     // MFMA C/D frag

typedef __attribute__((address_space(3))) unsigned int as3_u32;
typedef __attribute__((address_space(1))) unsigned int as1_u32;

#define VMCNT5 asm volatile("s_waitcnt vmcnt(5)" ::: "memory")
#define VMCNT4 asm volatile("s_waitcnt vmcnt(4)" ::: "memory")
#define VMCNT0 asm volatile("s_waitcnt vmcnt(0)" ::: "memory")
#define LGKM0  asm volatile("s_waitcnt lgkmcnt(0)" ::: "memory")
#define BARR() __builtin_amdgcn_s_barrier()
#define PRIO1  __builtin_amdgcn_s_setprio(1)
#define PRIO0  __builtin_amdgcn_s_setprio(0)

__device__ __forceinline__ unsigned short f2bf(float f) {
  unsigned u = __builtin_bit_cast(unsigned, f);
  u = (u + 0x7FFFu + ((u >> 16) & 1u)) >> 16;   // RNE
  return (unsigned short)u;
}

__device__ __forceinline__ f32x4 mfma16(short8 a, short8 b, f32x4 c) {
  return __builtin_amdgcn_mfma_f32_16x16x32_bf16(a, b, c, 0, 0, 0);
}

// 64-row x 72-elem (144B stride) bf16 scratch read.
__device__ __forceinline__ short8 rd72(const char* buf, int row, int kelem) {
  return *(const short8*)(buf + row * 144 + kelem * 2);
}

// Stage one 16KB chunk: 4 x global_load_lds dwordx4 per thread, linear LDS.
__device__ __forceinline__ void stage16k(char* ldsbase, const char* gsrc, int w, int lane) {
#pragma unroll
  for (int j = 0; j < 4; ++j) {
    int off = j * 4096 + w * 1024;
    __builtin_amdgcn_global_load_lds((const as1_u32*)(gsrc + off + lane * 16),
                                     (as3_u32*)(ldsbase + off), 16, 0, 0);
  }
}

// ============================ prep =========================================
__global__ void prep_kernel(const float* __restrict__ wqkv_f,
                            const float* __restrict__ wo_f,
                            const float* __restrict__ rel,
                            unsigned short* __restrict__ wt,
                            float* __restrict__ bias2d) {
  int b = blockIdx.x, tid = threadIdx.x;
  if (b < 128) {
    unsigned short* dst = wt + (size_t)b * 8192;
#pragma unroll
    for (int t = 0; t < 4; ++t) {
      int u = t * 256 + tid;          // 16B unit 0..1023
      int row = u >> 4, us = u & 15;
      int kg = (us & 8) | ((us ^ row) & 7);
      const float* src;
      if (b < 96) {                   // QKV chunk: h, rg, kc
        int h = b / 12, i = b % 12;
        int rg = i >> 2, kc = i & 3;
        src = wqkv_f + (size_t)(rg * 512 + h * 64 + row) * 512 + kc * 128 + kg * 8;
      } else {                        // Wo chunk: kc, ng
        int cw = b - 96;
        int kc = cw >> 3, ng = cw & 7;
        src = wo_f + (size_t)(ng * 64 + row) * 512 + kc * 128 + kg * 8;
      }
      float4 a = *(const float4*)src;
      float4 c = *(const float4*)(src + 4);
      unsigned p0 = (unsigned)f2bf(a.x) | ((unsigned)f2bf(a.y) << 16);
      unsigned p1 = (unsigned)f2bf(a.z) | ((unsigned)f2bf(a.w) << 16);
      unsigned p2 = (unsigned)f2bf(c.x) | ((unsigned)f2bf(c.y) << 16);
      unsigned p3 = (unsigned)f2bf(c.z) | ((unsigned)f2bf(c.w) << 16);
      *(uint4*)(dst + u * 8) = make_uint4(p0, p1, p2, p3);
    }
  } else {
    int idx = (b - 128) * 256 + tid;  // 0..4095
    int m = idx >> 6, nn = idx & 63;
    float s = 0.f;
#pragma unroll
    for (int hh = 0; hh < 8; ++hh) s += rel[hh * 16384 + m * 128 + nn];
    bias2d[idx] = s * 0.125f;
  }
}

// ============================ K2: attn_qkv =================================
__global__ __launch_bounds__(256, 2) void attn_qkv(
    const float* __restrict__ x,        // [2048,64,512] f32
    const char* __restrict__ wq,        // 96 x 16KB QKV chunks
    const float* __restrict__ bqkv,     // [1536]
    const float* __restrict__ bias2d,   // [64,64]
    char* __restrict__ ctxg) {          // d_out as ctx scratch (bf16)
  __shared__ __attribute__((aligned(16))) char smem[60416];
  char* B0 = smem;            // Q, then P
  char* B1 = smem + 9216;     // K
  char* B2 = smem + 18432;    // V^T, then ctx
  char* WSb = smem + 27648;   // 2 x 16KB weight stage

  const int n = blockIdx.x;
  const int tid = threadIdx.x;
  const int w = tid >> 6, lane = tid & 63;
  const int l15 = lane & 15, g = lane >> 4;
  const int wm = w >> 1, wn = w & 1;   // proj wave grid 2M x 2N
  const int mrow = w * 16 + g * 4;     // attn-phase C rows
  const int wrow = w * 16 + l15;       // attn-phase A row

  // bias2d into regs
  float b2d[16];
#pragma unroll
  for (int nt = 0; nt < 4; ++nt)
#pragma unroll
    for (int r = 0; r < 4; ++r)
      b2d[nt * 4 + r] = bias2d[(mrow + r) * 64 + nt * 16 + l15];

  stage16k(WSb, wq, w, lane);          // prologue: chunk 0 -> buf 0

  // x A-fragments: 2 m-tiles x 16 k-units, bf16
  short8 xf[32];
#pragma unroll
  for (int mt = 0; mt < 2; ++mt) {
    const float* xr = x + ((size_t)n * 64 + wm * 32 + mt * 16 + l15) * 512;
#pragma unroll
    for (int kk = 0; kk < 16; ++kk) {
      float4 a = *(const float4*)(xr + kk * 32 + g * 8);
      float4 c = *(const float4*)(xr + kk * 32 + g * 8 + 4);
      short8 s;
      s[0] = (short)f2bf(a.x); s[1] = (short)f2bf(a.y);
      s[2] = (short)f2bf(a.z); s[3] = (short)f2bf(a.w);
      s[4] = (short)f2bf(c.x); s[5] = (short)f2bf(c.y);
      s[6] = (short)f2bf(c.z); s[7] = (short)f2bf(c.w);
      xf[mt * 16 + kk] = s;
    }
  }

  int b = 0;
  for (int h = 0; h < 8; ++h) {
    // per-head biases for this wave's columns
    float bq2[2], bk2[2], bv2[2];
#pragma unroll
    for (int nt = 0; nt < 2; ++nt) {
      int col = h * 64 + wn * 32 + nt * 16 + l15;
      bq2[nt] = bqkv[col];
      bk2[nt] = bqkv[512 + col];
      bv2[nt] = bqkv[1024 + col];
    }
#pragma unroll
    for (int rg = 0; rg < 3; ++rg) {
      f32x4 acc[2][2] = {};
#pragma unroll
      for (int c = 0; c < 4; ++c) {
        if (b < 95)
          stage16k(WSb + (((b + 1) & 1) << 14), wq + (size_t)(b + 1) * 16384, w, lane);
        if (b < 95) { VMCNT4; } else { VMCNT0; }
        BARR();
        const char* ws = WSb + ((b & 1) << 14);
        PRIO1;
#pragma unroll
        for (int ks = 0; ks < 4; ++ks) {
#pragma unroll
          for (int nt = 0; nt < 2; ++nt) {
            int row = wn * 32 + nt * 16 + l15;
            int kg = ks * 4 + g;
            int us = (kg & 8) | ((kg ^ row) & 7);
            short8 bfr = *(const short8*)(ws + row * 256 + us * 16);
            acc[0][nt] = mfma16(xf[c * 4 + ks], bfr, acc[0][nt]);
            acc[1][nt] = mfma16(xf[16 + c * 4 + ks], bfr, acc[1][nt]);
          }
        }
        PRIO0;
        LGKM0; BARR();
        ++b;
      }
      // writeback to scratch
      if (rg == 0) {
#pragma unroll
        for (int mt = 0; mt < 2; ++mt)
#pragma unroll
          for (int nt = 0; nt < 2; ++nt)
#pragma unroll
            for (int r = 0; r < 4; ++r)
              *(unsigned short*)(B0 + (wm * 32 + mt * 16 + g * 4 + r) * 144 +
                                 (wn * 32 + nt * 16 + l15) * 2) =
                  f2bf(acc[mt][nt][r] + bq2[nt]);
      } else if (rg == 1) {
#pragma unroll
        for (int mt = 0; mt < 2; ++mt)
#pragma unroll
          for (int nt = 0; nt < 2; ++nt)
#pragma unroll
            for (int r = 0; r < 4; ++r)
              *(unsigned short*)(B1 + (wm * 32 + mt * 16 + g * 4 + r) * 144 +
                                 (wn * 32 + nt * 16 + l15) * 2) =
                  f2bf(acc[mt][nt][r] + bk2[nt]);
      } else {  // V transposed: Vt[d][tok]
#pragma unroll
        for (int mt = 0; mt < 2; ++mt)
#pragma unroll
          for (int nt = 0; nt < 2; ++nt) {
            unsigned short p0 = f2bf(acc[mt][nt][0] + bv2[nt]);
            unsigned short p1 = f2bf(acc[mt][nt][1] + bv2[nt]);
            unsigned short p2 = f2bf(acc[mt][nt][2] + bv2[nt]);
            unsigned short p3 = f2bf(acc[mt][nt][3] + bv2[nt]);
            unsigned lo = (unsigned)p0 | ((unsigned)p1 << 16);
            unsigned hi = (unsigned)p2 | ((unsigned)p3 << 16);
            *(uint2*)(B2 + (wn * 32 + nt * 16 + l15) * 144 +
                      (wm * 32 + mt * 16 + g * 4) * 2) = make_uint2(lo, hi);
          }
      }
    }
    LGKM0; BARR();   // Q/K/V scratch visible to all waves

    // ---- scores + softmax (M-split-4): P -> B0 (wave-local rows)
    {
      f32x4 sc[4] = {};
      short8 aq0 = rd72(B0, wrow, g * 8);
      short8 aq1 = rd72(B0, wrow, 32 + g * 8);
#pragma unroll
      for (int nt = 0; nt < 4; ++nt)
        sc[nt] = mfma16(aq0, rd72(B1, nt * 16 + l15, g * 8), sc[nt]);
#pragma unroll
      for (int nt = 0; nt < 4; ++nt)
        sc[nt] = mfma16(aq1, rd72(B1, nt * 16 + l15, 32 + g * 8), sc[nt]);
      float mx[4] = {-1e30f, -1e30f, -1e30f, -1e30f};
#pragma unroll
      for (int nt = 0; nt < 4; ++nt)
#pragma unroll
        for (int r = 0; r < 4; ++r) {
          float v = sc[nt][r] * 0.125f + b2d[nt * 4 + r];
          sc[nt][r] = v;
          mx[r] = fmaxf(mx[r], v);
        }
#pragma unroll
      for (int mk = 1; mk < 16; mk <<= 1)
#pragma unroll
        for (int r = 0; r < 4; ++r) mx[r] = fmaxf(mx[r], __shfl_xor(mx[r], mk));
      float sm[4] = {0.f, 0.f, 0.f, 0.f};
#pragma unroll
      for (int nt = 0; nt < 4; ++nt)
#pragma unroll
        for (int r = 0; r < 4; ++r) {
          float e = __expf(sc[nt][r] - mx[r]);
          sc[nt][r] = e;
          sm[r] += e;
        }
#pragma unroll
      for (int mk = 1; mk < 16; mk <<= 1)
#pragma unroll
        for (int r = 0; r < 4; ++r) sm[r] += __shfl_xor(sm[r], mk);
      float inv[4];
#pragma unroll
      for (int r = 0; r < 4; ++r) inv[r] = 1.0f / sm[r];
#pragma unroll
      for (int nt = 0; nt < 4; ++nt)
#pragma unroll
        for (int r = 0; r < 4; ++r)
          *(unsigned short*)(B0 + (mrow + r) * 144 + (nt * 16 + l15) * 2) =
              f2bf(sc[nt][r] * inv[r]);
    }

    // ---- PV: ctx rows (wave-local P, cross-wave Vt)
    f32x4 cv[4] = {};
    {
      short8 ap0 = rd72(B0, wrow, g * 8);
      short8 ap1 = rd72(B0, wrow, 32 + g * 8);
#pragma unroll
      for (int nt = 0; nt < 4; ++nt)
        cv[nt] = mfma16(ap0, rd72(B2, nt * 16 + l15, g * 8), cv[nt]);
#pragma unroll
      for (int nt = 0; nt < 4; ++nt)
        cv[nt] = mfma16(ap1, rd72(B2, nt * 16 + l15, 32 + g * 8), cv[nt]);
    }
    LGKM0; BARR();   // all PV reads of B2 done before overwrite
#pragma unroll
    for (int nt = 0; nt < 4; ++nt)
#pragma unroll
      for (int r = 0; r < 4; ++r)
        *(unsigned short*)(B2 + (mrow + r) * 144 + (nt * 16 + l15) * 2) =
            f2bf(cv[nt][r]);
    LGKM0; BARR();

    // ---- ctx copyout: coalesced, unit-swizzled for K3's linear staging
    {
      char* cdst = ctxg + (size_t)n * 131072 + (h >> 1) * 16384 + (h & 1) * 128;
#pragma unroll
      for (int it = 0; it < 2; ++it) {
        int flat = it * 256 + tid;
        int row = flat >> 3, uu = flat & 7;
        uint4 v = *(const uint4*)(B2 + row * 144 + uu * 16);
        int slot = uu ^ (row & 7);
        *(uint4*)(cdst + row * 256 + slot * 16) = v;
      }
    }
    // next head's bodies don't touch B2 for 12 bodies -> no barrier needed
  }
}

// ============================ K3: oproj_ln =================================
__global__ __launch_bounds__(256, 2) void oproj_ln(
    const char* __restrict__ ctxg,      // swizzled ctx chunks in d_out
    const char* __restrict__ wo,        // 32 x 16KB Wo chunks (ws + 96*16KB)
    const float* __restrict__ bo,
    const float* __restrict__ x,
    const float* __restrict__ lng,
    const float* __restrict__ lnb,
    float* __restrict__ out) {
  __shared__ __attribute__((aligned(16))) char smem[65536];
  char* WB = smem;            // 2 x 16KB Wo stage
  char* CB = smem + 32768;    // 2 x 16KB ctx stage
  float* EP  = (float*)smem;           // epilogue [64][68] f32 (overlays WB)
  float* SM1 = (float*)(smem + 32768); // [64][2] partial sums (overlays CB)
  float* SM2 = (float*)(smem + 33408);

  const int n = blockIdx.x;
  const int tid = threadIdx.x;
  const int w = tid >> 6, lane = tid & 63;
  const int l15 = lane & 15, g = lane >> 4;
  const int um = w >> 1, un = w & 1;

  const char* cbase = ctxg + (size_t)n * 131072;

  // prologue: ctx chunk 0 and Wo chunk 0
  stage16k(CB, cbase, w, lane);
  stage16k(WB, wo, w, lane);

  f32x4 acc[8][2][2] = {};

  for (int kc = 0; kc < 4; ++kc) {
    short8 actx[2][4];
#pragma unroll
    for (int ng = 0; ng < 8; ++ng) {
      int b = kc * 8 + ng;
      if (b < 31)
        stage16k(WB + (((b + 1) & 1) << 14), wo + (size_t)(b + 1) * 16384, w, lane);
      if ((ng & 1) == 0 && kc < 3) {  // ctx piece (ng>>1) of chunk kc+1
        int p = ng >> 1;
        int off = p * 4096 + w * 1024;
        __builtin_amdgcn_global_load_lds(
            (const as1_u32*)(cbase + (kc + 1) * 16384 + off + lane * 16),
            (as3_u32*)(CB + (((kc + 1) & 1) << 14) + off), 16, 0, 0);
      }
      if (b < 31) { VMCNT5; } else { VMCNT0; }
      BARR();
      const char* cb = CB + ((kc & 1) << 14);
      if (ng == 0) {
#pragma unroll
        for (int mt = 0; mt < 2; ++mt)
#pragma unroll
          for (int ks = 0; ks < 4; ++ks) {
            int row = um * 32 + mt * 16 + l15;
            int u = ks * 4 + g;
            int us = u ^ (row & 7);
            actx[mt][ks] = *(const short8*)(cb + row * 256 + us * 16);
          }
      }
      const char* ws = WB + ((b & 1) << 14);
      PRIO1;
#pragma unroll
      for (int ks = 0; ks < 4; ++ks) {
#pragma unroll
        for (int nt = 0; nt < 2; ++nt) {
          int row = un * 32 + nt * 16 + l15;
          int kg = ks * 4 + g;
          int us = (kg & 8) | ((kg ^ row) & 7);
          short8 bfr = *(const short8*)(ws + row * 256 + us * 16);
          acc[ng][0][nt] = mfma16(actx[0][ks], bfr, acc[ng][0][nt]);
          acc[ng][1][nt] = mfma16(actx[1][ks], bfr, acc[ng][1][nt]);
        }
      }
      PRIO0;
      LGKM0; BARR();
    }
  }

  // ================= epilogue: +bo, +residual, LayerNorm ===================
  VMCNT0;
  const float* xblk = x + (size_t)n * 32768;
  float* oblk = out + (size_t)n * 32768;
  float s1[2][4] = {}, s2[2][4] = {};

#pragma unroll
  for (int ng = 0; ng < 8; ++ng) {
    // stage x chunk [64][64] f32 -> EP
#pragma unroll
    for (int t = 0; t < 4; ++t) {
      int flat = t * 256 + tid;
      int row = flat >> 4, f4 = flat & 15;
      float4 v = *(const float4*)(xblk + row * 512 + ng * 64 + f4 * 4);
      *(float4*)(EP + row * 68 + f4 * 4) = v;
    }
    LGKM0; BARR();
    float boA[2];
#pragma unroll
    for (int nt = 0; nt < 2; ++nt) boA[nt] = bo[ng * 64 + un * 32 + nt * 16 + l15];
#pragma unroll
    for (int mt = 0; mt < 2; ++mt)
#pragma unroll
      for (int nt = 0; nt < 2; ++nt)
#pragma unroll
        for (int r = 0; r < 4; ++r) {
          int row = um * 32 + mt * 16 + g * 4 + r;
          float xv = EP[row * 68 + un * 32 + nt * 16 + l15];
          float v = acc[ng][mt][nt][r] + boA[nt] + xv;
          acc[ng][mt][nt][r] = v;
          s1[mt][r] += v;
          s2[mt][r] += v * v;
        }
    LGKM0; BARR();
  }
  // cross-lane then cross-wave (un) row reductions
#pragma unroll
  for (int mk = 1; mk < 16; mk <<= 1)
#pragma unroll
    for (int mt = 0; mt < 2; ++mt)
#pragma unroll
      for (int r = 0; r < 4; ++r) {
        s1[mt][r] += __shfl_xor(s1[mt][r], mk);
        s2[mt][r] += __shfl_xor(s2[mt][r], mk);
      }
  if (l15 == 0) {
#pragma unroll
    for (int mt = 0; mt < 2; ++mt)
#pragma unroll
      for (int r = 0; r < 4; ++r) {
        int row = um * 32 + mt * 16 + g * 4 + r;
        SM1[row * 2 + un] = s1[mt][r];
        SM2[row * 2 + un] = s2[mt][r];
      }
  }
  LGKM0; BARR();
  float mu[2][4], rs[2][4];
#pragma unroll
  for (int mt = 0; mt < 2; ++mt)
#pragma unroll
    for (int r = 0; r < 4; ++r) {
      int row = um * 32 + mt * 16 + g * 4 + r;
      float a1 = SM1[row * 2] + SM1[row * 2 + 1];
      float a2 = SM2[row * 2] + SM2[row * 2 + 1];
      float m = a1 * (1.0f / 512.0f);
      float var = a2 * (1.0f / 512.0f) - m * m;
      mu[mt][r] = m;
      rs[mt][r] = rsqrtf(var + 1e-5f);
    }
  BARR();
#pragma unroll
  for (int ng = 0; ng < 8; ++ng) {
    float lgA[2], lbA[2];
#pragma unroll
    for (int nt = 0; nt < 2; ++nt) {
      int col = ng * 64 + un * 32 + nt * 16 + l15;
      lgA[nt] = lng[col];
      lbA[nt] = lnb[col];
    }
#pragma unroll
    for (int mt = 0; mt < 2; ++mt)
#pragma unroll
      for (int nt = 0; nt < 2; ++nt)
#pragma unroll
        for (int r = 0; r < 4; ++r) {
          int row = um * 32 + mt * 16 + g * 4 + r;
          EP[row * 68 + un * 32 + nt * 16 + l15] =
              (acc[ng][mt][nt][r] - mu[mt][r]) * rs[mt][r] * lgA[nt] + lbA[nt];
        }
    LGKM0; BARR();
#pragma unroll
    for (int t = 0; t < 4; ++t) {
      int flat = t * 256 + tid;
      int row = flat >> 4, f4 = flat & 15;
      *(float4*)(oblk + row * 512 + ng * 64 + f4 * 4) =
          *(const float4*)(EP + row * 68 + f4 * 4);
    }
    BARR();
  }
}

// ============================ launch =======================================
extern "C" void kernel_launch(void* const* d_in, const int* in_sizes, int n_in,
                              void* d_out, int out_size, void* d_ws, size_t ws_size,
                              hipStream_t stream) {
  const float* x    = (const float*)d_in[0];
  const float* wqkv = (const float*)d_in[1];
  const float* bqkv = (const float*)d_in[2];
  const float* wo   = (const float*)d_in[3];
  const float* bo   = (const float*)d_in[4];
  const float* lng  = (const float*)d_in[5];
  const float* lnb  = (const float*)d_in[6];
  const float* rel  = (const float*)d_in[7];

  // ws: 96 QKV chunks + 32 Wo chunks (16KB each) | bias2d f32 16KB
  unsigned short* wt = (unsigned short*)d_ws;
  float* bias2d = (float*)((char*)d_ws + 128 * 16384);
  const char* wqc = (const char*)d_ws;
  const char* woc = (const char*)d_ws + 96 * 16384;

  prep_kernel<<<144, 256, 0, stream>>>(wqkv, wo, rel, wt, bias2d);
  attn_qkv<<<2048, 256, 0, stream>>>(x, wqc, bqkv, bias2d, (char*)d_out);
  oproj_ln<<<2048, 256, 0, stream>>>((const char*)d_out, woc, bo, x, lng, lnb,
                                     (float*)d_out);
}

// Round 5
// 548.239 us; speedup vs baseline: 2.4796x; 1.0546x over previous
//
#include <hip/hip_runtime.h>
#include <stdint.h>
#include <stddef.h>

// ---------------------------------------------------------------------------
// EnhancedSpatialAttention, round 5 (MI355X / gfx950).
//   prep_kernel : weights -> bf16 pre-tiled/pre-swizzled 16KB chunks + bias2d.
//   attn_qkv    : per-sequence fused QKV proj + attention. Depth-2 counted
//                 vmcnt pipeline over 3x16KB staging buffers (dynamic LDS
//                 72KB, 2 blocks/CU); 128B-stride XOR-swizzled scratch;
//                 full-line 8KB/head ctx copyout into d_out's front half.
//   oproj_ln    : per-sequence pipelined GEMM ctx@Wo^T + bias + residual + LN,
//                 in-place over d_out (ctx stride 128KB = self-overlap only).
// ---------------------------------------------------------------------------

typedef __attribute__((ext_vector_type(8))) short short8;    // 8 bf16
typedef __attribute__((ext_vector_type(4))) float f32x4;     // MFMA C/D frag

typedef __attribute__((address_space(3))) unsigned int as3_u32;
typedef __attribute__((address_space(1))) unsigned int as1_u32;

#define VMCNT8 asm volatile("s_waitcnt vmcnt(8)" ::: "memory")
#define VMCNT5 asm volatile("s_waitcnt vmcnt(5)" ::: "memory")
#define VMCNT4 asm volatile("s_waitcnt vmcnt(4)" ::: "memory")
#define VMCNT0 asm volatile("s_waitcnt vmcnt(0)" ::: "memory")
#define LGKM0  asm volatile("s_waitcnt lgkmcnt(0)" ::: "memory")
#define BARR() __builtin_amdgcn_s_barrier()
#define PRIO1  __builtin_amdgcn_s_setprio(1)
#define PRIO0  __builtin_amdgcn_s_setprio(0)

__device__ __forceinline__ unsigned short f2bf(float f) {
  unsigned u = __builtin_bit_cast(unsigned, f);
  u = (u + 0x7FFFu + ((u >> 16) & 1u)) >> 16;   // RNE
  return (unsigned short)u;
}

__device__ __forceinline__ f32x4 mfma16(short8 a, short8 b, f32x4 c) {
  return __builtin_amdgcn_mfma_f32_16x16x32_bf16(a, b, c, 0, 0, 0);
}

// 64-row x 64-col bf16 scratch, 128B row stride, 16B-unit XOR swizzle.
__device__ __forceinline__ short8 rd8s(const char* buf, int row, int unit) {
  return *(const short8*)(buf + row * 128 + ((unit ^ (row & 7)) * 16));
}
__device__ __forceinline__ void wr2s(char* buf, int row, int col, unsigned short v) {
  int slot = (col >> 3) ^ (row & 7);
  *(unsigned short*)(buf + row * 128 + slot * 16 + (col & 7) * 2) = v;
}
__device__ __forceinline__ void wr8s(char* buf, int row, int col, uint2 v) {
  int slot = (col >> 3) ^ (row & 7);
  *(uint2*)(buf + row * 128 + slot * 16 + (col & 7) * 2) = v;
}

// Stage one 16KB chunk: 4 x global_load_lds dwordx4 per thread, linear LDS.
__device__ __forceinline__ void stage16k(char* ldsbase, const char* gsrc, int w, int lane) {
#pragma unroll
  for (int j = 0; j < 4; ++j) {
    int off = j * 4096 + w * 1024;
    __builtin_amdgcn_global_load_lds((const as1_u32*)(gsrc + off + lane * 16),
                                     (as3_u32*)(ldsbase + off), 16, 0, 0);
  }
}

// ============================ prep =========================================
__global__ void prep_kernel(const float* __restrict__ wqkv_f,
                            const float* __restrict__ wo_f,
                            const float* __restrict__ rel,
                            unsigned short* __restrict__ wt,
                            float* __restrict__ bias2d) {
  int b = blockIdx.x, tid = threadIdx.x;
  if (b < 128) {
    unsigned short* dst = wt + (size_t)b * 8192;
#pragma unroll
    for (int t = 0; t < 4; ++t) {
      int u = t * 256 + tid;          // 16B unit 0..1023
      int row = u >> 4, us = u & 15;
      int kg = (us & 8) | ((us ^ row) & 7);
      const float* src;
      if (b < 96) {                   // QKV chunk: h, rg, kc
        int h = b / 12, i = b % 12;
        int rg = i >> 2, kc = i & 3;
        src = wqkv_f + (size_t)(rg * 512 + h * 64 + row) * 512 + kc * 128 + kg * 8;
      } else {                        // Wo chunk: kc, ng
        int cw = b - 96;
        int kc = cw >> 3, ng = cw & 7;
        src = wo_f + (size_t)(ng * 64 + row) * 512 + kc * 128 + kg * 8;
      }
      float4 a = *(const float4*)src;
      float4 c = *(const float4*)(src + 4);
      unsigned p0 = (unsigned)f2bf(a.x) | ((unsigned)f2bf(a.y) << 16);
      unsigned p1 = (unsigned)f2bf(a.z) | ((unsigned)f2bf(a.w) << 16);
      unsigned p2 = (unsigned)f2bf(c.x) | ((unsigned)f2bf(c.y) << 16);
      unsigned p3 = (unsigned)f2bf(c.z) | ((unsigned)f2bf(c.w) << 16);
      *(uint4*)(dst + u * 8) = make_uint4(p0, p1, p2, p3);
    }
  } else {
    int idx = (b - 128) * 256 + tid;  // 0..4095
    int m = idx >> 6, nn = idx & 63;
    float s = 0.f;
#pragma unroll
    for (int hh = 0; hh < 8; ++hh) s += rel[hh * 16384 + m * 128 + nn];
    bias2d[idx] = s * 0.125f;
  }
}

// ============================ K2: attn_qkv =================================
__global__ __launch_bounds__(256, 2) void attn_qkv(
    const float* __restrict__ x,        // [2048,64,512] f32
    const char* __restrict__ wq,        // 96 x 16KB QKV chunks
    const float* __restrict__ bqkv,     // [1536]
    const float* __restrict__ bias2d,   // [64,64]
    char* __restrict__ ctxg) {          // d_out as ctx scratch (bf16)
  extern __shared__ __attribute__((aligned(16))) char smem[];  // 73728 B
  char* WS = smem;                 // 3 x 16KB staging
  char* B0 = smem + 49152;         // Q, then P (8KB swizzled)
  char* B1 = smem + 57344;         // K, then ctx
  char* B2 = smem + 65536;         // V^T

  const int n = blockIdx.x;
  const int tid = threadIdx.x;
  const int w = tid >> 6, lane = tid & 63;
  const int l15 = lane & 15, g = lane >> 4;
  const int wm = w >> 1, wn = w & 1;   // proj wave grid 2M x 2N
  const int mrow = w * 16 + g * 4;     // attn-phase C rows
  const int wrow = w * 16 + l15;       // attn-phase A row

  // ---- x A-fragments first (oldest in vmem queue)
  short8 xf[32];
#pragma unroll
  for (int mt = 0; mt < 2; ++mt) {
    const float* xr = x + ((size_t)n * 64 + wm * 32 + mt * 16 + l15) * 512;
#pragma unroll
    for (int kk = 0; kk < 16; ++kk) {
      float4 a = *(const float4*)(xr + kk * 32 + g * 8);
      float4 c = *(const float4*)(xr + kk * 32 + g * 8 + 4);
      short8 s;
      s[0] = (short)f2bf(a.x); s[1] = (short)f2bf(a.y);
      s[2] = (short)f2bf(a.z); s[3] = (short)f2bf(a.w);
      s[4] = (short)f2bf(c.x); s[5] = (short)f2bf(c.y);
      s[6] = (short)f2bf(c.z); s[7] = (short)f2bf(c.w);
      xf[mt * 16 + kk] = s;
    }
  }
  float b2d[16];
#pragma unroll
  for (int nt = 0; nt < 4; ++nt)
#pragma unroll
    for (int r = 0; r < 4; ++r)
      b2d[nt * 4 + r] = bias2d[(mrow + r) * 64 + nt * 16 + l15];

  // prologue: chunks 0,1 -> bufs 0,1
  stage16k(WS, wq, w, lane);
  stage16k(WS + 16384, wq + 16384, w, lane);

  int b = 0, cur = 0;
  for (int h = 0; h < 8; ++h) {
    float bq2[2], bk2[2], bv2[2];
#pragma unroll
    for (int nt = 0; nt < 2; ++nt) {
      int col = h * 64 + wn * 32 + nt * 16 + l15;
      bq2[nt] = bqkv[col];
      bk2[nt] = bqkv[512 + col];
      bv2[nt] = bqkv[1024 + col];
    }
#pragma unroll
    for (int rg = 0; rg < 3; ++rg) {
      f32x4 acc[2][2] = {};
#pragma unroll
      for (int c = 0; c < 4; ++c) {
        int tgt = cur + 2; if (tgt >= 3) tgt -= 3;
        if (b + 2 < 96) {
          stage16k(WS + tgt * 16384, wq + (size_t)(b + 2) * 16384, w, lane);
          VMCNT8;
        } else if (b + 1 < 96) { VMCNT4; } else { VMCNT0; }
        BARR();
        const char* ws = WS + cur * 16384;
        PRIO1;
#pragma unroll
        for (int ks = 0; ks < 4; ++ks) {
#pragma unroll
          for (int nt = 0; nt < 2; ++nt) {
            int row = wn * 32 + nt * 16 + l15;
            int kg = ks * 4 + g;
            int us = (kg & 8) | ((kg ^ row) & 7);
            short8 bfr = *(const short8*)(ws + row * 256 + us * 16);
            acc[0][nt] = mfma16(xf[c * 4 + ks], bfr, acc[0][nt]);
            acc[1][nt] = mfma16(xf[16 + c * 4 + ks], bfr, acc[1][nt]);
          }
        }
        PRIO0;
        LGKM0; BARR();
        ++b; ++cur; if (cur >= 3) cur -= 3;
      }
      // writeback to swizzled scratch
      if (rg == 0) {
#pragma unroll
        for (int mt = 0; mt < 2; ++mt)
#pragma unroll
          for (int nt = 0; nt < 2; ++nt)
#pragma unroll
            for (int r = 0; r < 4; ++r)
              wr2s(B0, wm * 32 + mt * 16 + g * 4 + r, wn * 32 + nt * 16 + l15,
                   f2bf(acc[mt][nt][r] + bq2[nt]));
      } else if (rg == 1) {
#pragma unroll
        for (int mt = 0; mt < 2; ++mt)
#pragma unroll
          for (int nt = 0; nt < 2; ++nt)
#pragma unroll
            for (int r = 0; r < 4; ++r)
              wr2s(B1, wm * 32 + mt * 16 + g * 4 + r, wn * 32 + nt * 16 + l15,
                   f2bf(acc[mt][nt][r] + bk2[nt]));
      } else {  // V transposed: Vt[d][tok], 4 toks per uint2
#pragma unroll
        for (int mt = 0; mt < 2; ++mt)
#pragma unroll
          for (int nt = 0; nt < 2; ++nt) {
            unsigned short p0 = f2bf(acc[mt][nt][0] + bv2[nt]);
            unsigned short p1 = f2bf(acc[mt][nt][1] + bv2[nt]);
            unsigned short p2 = f2bf(acc[mt][nt][2] + bv2[nt]);
            unsigned short p3 = f2bf(acc[mt][nt][3] + bv2[nt]);
            unsigned lo = (unsigned)p0 | ((unsigned)p1 << 16);
            unsigned hi = (unsigned)p2 | ((unsigned)p3 << 16);
            wr8s(B2, wn * 32 + nt * 16 + l15, wm * 32 + mt * 16 + g * 4,
                 make_uint2(lo, hi));
          }
      }
    }
    LGKM0; BARR();   // Q/K/Vt visible to all waves

    // ---- scores + softmax: P -> B0 (wave-own rows)
    {
      f32x4 sc[4] = {};
      short8 aq0 = rd8s(B0, wrow, g);
      short8 aq1 = rd8s(B0, wrow, 4 + g);
#pragma unroll
      for (int nt = 0; nt < 4; ++nt)
        sc[nt] = mfma16(aq0, rd8s(B1, nt * 16 + l15, g), sc[nt]);
#pragma unroll
      for (int nt = 0; nt < 4; ++nt)
        sc[nt] = mfma16(aq1, rd8s(B1, nt * 16 + l15, 4 + g), sc[nt]);
      float mx[4] = {-1e30f, -1e30f, -1e30f, -1e30f};
#pragma unroll
      for (int nt = 0; nt < 4; ++nt)
#pragma unroll
        for (int r = 0; r < 4; ++r) {
          float v = sc[nt][r] * 0.125f + b2d[nt * 4 + r];
          sc[nt][r] = v;
          mx[r] = fmaxf(mx[r], v);
        }
#pragma unroll
      for (int mk = 1; mk < 16; mk <<= 1)
#pragma unroll
        for (int r = 0; r < 4; ++r) mx[r] = fmaxf(mx[r], __shfl_xor(mx[r], mk));
      float sm[4] = {0.f, 0.f, 0.f, 0.f};
#pragma unroll
      for (int nt = 0; nt < 4; ++nt)
#pragma unroll
        for (int r = 0; r < 4; ++r) {
          float e = __expf(sc[nt][r] - mx[r]);
          sc[nt][r] = e;
          sm[r] += e;
        }
#pragma unroll
      for (int mk = 1; mk < 16; mk <<= 1)
#pragma unroll
        for (int r = 0; r < 4; ++r) sm[r] += __shfl_xor(sm[r], mk);
      float inv[4];
#pragma unroll
      for (int r = 0; r < 4; ++r) inv[r] = 1.0f / sm[r];
#pragma unroll
      for (int nt = 0; nt < 4; ++nt)
#pragma unroll
        for (int r = 0; r < 4; ++r)
          wr2s(B0, mrow + r, nt * 16 + l15, f2bf(sc[nt][r] * inv[r]));
    }

    // ---- PV (P own rows in-wave; Vt stable since pre-scores barrier)
    f32x4 cv[4] = {};
    {
      short8 ap0 = rd8s(B0, wrow, g);
      short8 ap1 = rd8s(B0, wrow, 4 + g);
#pragma unroll
      for (int nt = 0; nt < 4; ++nt)
        cv[nt] = mfma16(ap0, rd8s(B2, nt * 16 + l15, g), cv[nt]);
#pragma unroll
      for (int nt = 0; nt < 4; ++nt)
        cv[nt] = mfma16(ap1, rd8s(B2, nt * 16 + l15, 4 + g), cv[nt]);
    }
    BARR();   // all waves' K reads (scores) complete before ctx overwrites B1
#pragma unroll
    for (int nt = 0; nt < 4; ++nt)
#pragma unroll
      for (int r = 0; r < 4; ++r)
        wr2s(B1, mrow + r, nt * 16 + l15, f2bf(cv[nt][r]));
    LGKM0; BARR();

    // ---- ctx copyout: contiguous 8KB/head, swizzle cancels (slot->slot)
    {
      char* cdst = ctxg + (size_t)n * 131072 + h * 8192;
#pragma unroll
      for (int it = 0; it < 2; ++it) {
        int flat = it * 256 + tid;
        int row = flat >> 3, s = flat & 7;
        uint4 v = *(const uint4*)(B1 + row * 128 + s * 16);
        *(uint4*)(cdst + row * 128 + s * 16) = v;
      }
    }
  }
}

// ============================ K3: oproj_ln =================================
__global__ __launch_bounds__(256, 2) void oproj_ln(
    const char* __restrict__ ctxg,      // 8KB/head ctx blocks in d_out
    const char* __restrict__ wo,        // 32 x 16KB Wo chunks
    const float* __restrict__ bo,
    const float* __restrict__ x,
    const float* __restrict__ lng,
    const float* __restrict__ lnb,
    float* __restrict__ out) {
  __shared__ __attribute__((aligned(16))) char smem[65536];
  char* WB = smem;            // 2 x 16KB Wo stage
  char* CB = smem + 32768;    // 2 x 16KB ctx stage (2 heads x 8KB each)
  float* EP  = (float*)smem;           // epilogue [64][68] f32 (overlays WB)
  float* SM1 = (float*)(smem + 32768); // [64][2] partials (overlays CB)
  float* SM2 = (float*)(smem + 33408);

  const int n = blockIdx.x;
  const int tid = threadIdx.x;
  const int w = tid >> 6, lane = tid & 63;
  const int l15 = lane & 15, g = lane >> 4;
  const int um = w >> 1, un = w & 1;

  const char* cbase = ctxg + (size_t)n * 131072;

  stage16k(CB, cbase, w, lane);
  stage16k(WB, wo, w, lane);

  f32x4 acc[8][2][2] = {};

  for (int kc = 0; kc < 4; ++kc) {
    short8 actx[2][4];
#pragma unroll
    for (int ng = 0; ng < 8; ++ng) {
      int b = kc * 8 + ng;
      if (b < 31)
        stage16k(WB + (((b + 1) & 1) << 14), wo + (size_t)(b + 1) * 16384, w, lane);
      if ((ng & 1) == 0 && kc < 3) {  // ctx piece (ng>>1) of chunk kc+1
        int p = ng >> 1;
        int off = p * 4096 + w * 1024;
        __builtin_amdgcn_global_load_lds(
            (const as1_u32*)(cbase + (kc + 1) * 16384 + off + lane * 16),
            (as3_u32*)(CB + (((kc + 1) & 1) << 14) + off), 16, 0, 0);
      }
      if (b < 31) { VMCNT5; } else { VMCNT0; }
      BARR();
      const char* cb = CB + ((kc & 1) << 14);
      if (ng == 0) {
#pragma unroll
        for (int mt = 0; mt < 2; ++mt)
#pragma unroll
          for (int ks = 0; ks < 4; ++ks) {
            int row = um * 32 + mt * 16 + l15;
            int u = ks * 4 + g;   // k-unit: head = u>>3, unit-in-head = u&7
            actx[mt][ks] = *(const short8*)(cb + (u >> 3) * 8192 + row * 128 +
                                            (((u & 7) ^ (row & 7)) * 16));
          }
      }
      const char* ws = WB + ((b & 1) << 14);
      PRIO1;
#pragma unroll
      for (int ks = 0; ks < 4; ++ks) {
#pragma unroll
        for (int nt = 0; nt < 2; ++nt) {
          int row = un * 32 + nt * 16 + l15;
          int kg = ks * 4 + g;
          int us = (kg & 8) | ((kg ^ row) & 7);
          short8 bfr = *(const short8*)(ws + row * 256 + us * 16);
          acc[ng][0][nt] = mfma16(actx[0][ks], bfr, acc[ng][0][nt]);
          acc[ng][1][nt] = mfma16(actx[1][ks], bfr, acc[ng][1][nt]);
        }
      }
      PRIO0;
      LGKM0; BARR();
    }
  }

  // ================= epilogue: +bo, +residual, LayerNorm ===================
  VMCNT0;
  const float* xblk = x + (size_t)n * 32768;
  float* oblk = out + (size_t)n * 32768;
  float s1[2][4] = {}, s2[2][4] = {};

#pragma unroll
  for (int ng = 0; ng < 8; ++ng) {
#pragma unroll
    for (int t = 0; t < 4; ++t) {
      int flat = t * 256 + tid;
      int row = flat >> 4, f4 = flat & 15;
      float4 v = *(const float4*)(xblk + row * 512 + ng * 64 + f4 * 4);
      *(float4*)(EP + row * 68 + f4 * 4) = v;
    }
    LGKM0; BARR();
    float boA[2];
#pragma unroll
    for (int nt = 0; nt < 2; ++nt) boA[nt] = bo[ng * 64 + un * 32 + nt * 16 + l15];
#pragma unroll
    for (int mt = 0; mt < 2; ++mt)
#pragma unroll
      for (int nt = 0; nt < 2; ++nt)
#pragma unroll
        for (int r = 0; r < 4; ++r) {
          int row = um * 32 + mt * 16 + g * 4 + r;
          float xv = EP[row * 68 + un * 32 + nt * 16 + l15];
          float v = acc[ng][mt][nt][r] + boA[nt] + xv;
          acc[ng][mt][nt][r] = v;
          s1[mt][r] += v;
          s2[mt][r] += v * v;
        }
    LGKM0; BARR();
  }
#pragma unroll
  for (int mk = 1; mk < 16; mk <<= 1)
#pragma unroll
    for (int mt = 0; mt < 2; ++mt)
#pragma unroll
      for (int r = 0; r < 4; ++r) {
        s1[mt][r] += __shfl_xor(s1[mt][r], mk);
        s2[mt][r] += __shfl_xor(s2[mt][r], mk);
      }
  if (l15 == 0) {
#pragma unroll
    for (int mt = 0; mt < 2; ++mt)
#pragma unroll
      for (int r = 0; r < 4; ++r) {
        int row = um * 32 + mt * 16 + g * 4 + r;
        SM1[row * 2 + un] = s1[mt][r];
        SM2[row * 2 + un] = s2[mt][r];
      }
  }
  LGKM0; BARR();
  float mu[2][4], rs[2][4];
#pragma unroll
  for (int mt = 0; mt < 2; ++mt)
#pragma unroll
    for (int r = 0; r < 4; ++r) {
      int row = um * 32 + mt * 16 + g * 4 + r;
      float a1 = SM1[row * 2] + SM1[row * 2 + 1];
      float a2 = SM2[row * 2] + SM2[row * 2 + 1];
      float m = a1 * (1.0f / 512.0f);
      float var = a2 * (1.0f / 512.0f) - m * m;
      mu[mt][r] = m;
      rs[mt][r] = rsqrtf(var + 1e-5f);
    }
  BARR();
#pragma unroll
  for (int ng = 0; ng < 8; ++ng) {
    float lgA[2], lbA[2];
#pragma unroll
    for (int nt = 0; nt < 2; ++nt) {
      int col = ng * 64 + un * 32 + nt * 16 + l15;
      lgA[nt] = lng[col];
      lbA[nt] = lnb[col];
    }
#pragma unroll
    for (int mt = 0; mt < 2; ++mt)
#pragma unroll
      for (int nt = 0; nt < 2; ++nt)
#pragma unroll
        for (int r = 0; r < 4; ++r) {
          int row = um * 32 + mt * 16 + g * 4 + r;
          EP[row * 68 + un * 32 + nt * 16 + l15] =
              (acc[ng][mt][nt][r] - mu[mt][r]) * rs[mt][r] * lgA[nt] + lbA[nt];
        }
    LGKM0; BARR();
#pragma unroll
    for (int t = 0; t < 4; ++t) {
      int flat = t * 256 + tid;
      int row = flat >> 4, f4 = flat & 15;
      *(float4*)(oblk + row * 512 + ng * 64 + f4 * 4) =
          *(const float4*)(EP + row * 68 + f4 * 4);
    }
    BARR();
  }
}

// ============================ launch =======================================
extern "C" void kernel_launch(void* const* d_in, const int* in_sizes, int n_in,
                              void* d_out, int out_size, void* d_ws, size_t ws_size,
                              hipStream_t stream) {
  const float* x    = (const float*)d_in[0];
  const float* wqkv = (const float*)d_in[1];
  const float* bqkv = (const float*)d_in[2];
  const float* wo   = (const float*)d_in[3];
  const float* bo   = (const float*)d_in[4];
  const float* lng  = (const float*)d_in[5];
  const float* lnb  = (const float*)d_in[6];
  const float* rel  = (const float*)d_in[7];

  // ws: 96 QKV chunks + 32 Wo chunks (16KB each) | bias2d f32 16KB
  unsigned short* wt = (unsigned short*)d_ws;
  float* bias2d = (float*)((char*)d_ws + 128 * 16384);
  const char* wqc = (const char*)d_ws;
  const char* woc = (const char*)d_ws + 96 * 16384;

  hipFuncSetAttribute(reinterpret_cast<const void*>(attn_qkv),
                      hipFuncAttributeMaxDynamicSharedMemorySize, 73728);

  prep_kernel<<<144, 256, 0, stream>>>(wqkv, wo, rel, wt, bias2d);
  attn_qkv<<<2048, 256, 73728, stream>>>(x, wqc, bqkv, bias2d, (char*)d_out);
  oproj_ln<<<2048, 256, 0, stream>>>((const char*)d_out, woc, bo, x, lng, lnb,
                                     (float*)d_out);
}